// Round 19
// baseline (46.729 us; speedup 1.0000x reference)
//
#include <hip/hip_runtime.h>
#include <hip/hip_bf16.h>
#include <math.h>

#define D_SINGLE 512
#define D_PAIR   128
#define RANK     32
#define NROW     512
#define EPS      1e-5f

typedef __attribute__((ext_vector_type(8))) short bf16x8;  // 8 bf16 = 4 VGPRs
typedef __attribute__((ext_vector_type(4))) float f32x4;

// ---------------------------------------------------------------------------
// Kernel 1 (r8 winner, verbatim): per-row LayerNorm + low-rank projection.
// ---------------------------------------------------------------------------
__global__ __launch_bounds__(256) void k1_ln_proj(
    const float* __restrict__ xa, const float* __restrict__ xb,
    const float* __restrict__ ln_g, const float* __restrict__ ln_b,
    const float* __restrict__ wl, const float* __restrict__ bl,
    const float* __restrict__ wr, const float* __restrict__ br,
    __hip_bfloat16* __restrict__ a_bf, float* __restrict__ b_proj)
{
    const int bid  = blockIdx.x;
    const int row  = bid & (NROW - 1);
    const bool isb = bid >= NROW;
    const float* x    = (isb ? xb : xa) + row * D_SINGLE;
    const float* W    = isb ? wr : wl;
    const float* bias = isb ? br : bl;
    float*           outf = b_proj + row * RANK;
    __hip_bfloat16*  outh = a_bf   + row * RANK;

    __shared__ float xn[D_SINGLE];
    __shared__ float red[8];

    const int t    = threadIdx.x;
    const int wave = t >> 6;
    const int lane = t & 63;

    float x0 = x[t], x1 = x[t + 256];
    float s  = x0 + x1;
    float ss = x0 * x0 + x1 * x1;
    #pragma unroll
    for (int m = 1; m < 64; m <<= 1) {
        s  += __shfl_xor(s, m);
        ss += __shfl_xor(ss, m);
    }
    if (lane == 0) { red[wave] = s; red[4 + wave] = ss; }
    __syncthreads();
    float S    = red[0] + red[1] + red[2] + red[3];
    float SS   = red[4] + red[5] + red[6] + red[7];
    float mean = S * (1.0f / D_SINGLE);
    float var  = SS * (1.0f / D_SINGLE) - mean * mean;
    float rstd = rsqrtf(var + EPS);
    xn[t]       = (x0 - mean) * rstd * ln_g[t]       + ln_b[t];
    xn[t + 256] = (x1 - mean) * rstd * ln_g[t + 256] + ln_b[t + 256];
    __syncthreads();

    #pragma unroll
    for (int q = 0; q < 8; ++q) {
        int r = wave + 4 * q;
        float acc = 0.f;
        #pragma unroll
        for (int tt = 0; tt < 8; ++tt) {
            int k = lane + 64 * tt;
            acc += xn[k] * W[r * D_SINGLE + k];
        }
        #pragma unroll
        for (int m = 1; m < 64; m <<= 1) acc += __shfl_xor(acc, m);
        if (lane == 0) {
            float v = acc + bias[r];
            if (isb) outf[r] = v;
            else     outh[r] = __float2bfloat16(v);
        }
    }
}

// ---------------------------------------------------------------------------
// Kernel 2 (r8 winner, verbatim): wb[j][p*32+r] = sum_s b[j][s]*w_out[p][r*32+s]
// ---------------------------------------------------------------------------
__global__ __launch_bounds__(256) void k2_wb(
    const float* __restrict__ bproj, const float* __restrict__ w_out,
    __hip_bfloat16* __restrict__ wb)
{
    const int g = blockIdx.x >> 4;   // j-group (8 rows of b)
    const int c = blockIdx.x & 15;   // pr chunk
    const int t = threadIdx.x;

    __shared__ float bl[8 * RANK];
    bl[t] = bproj[g * 8 * RANK + t];
    __syncthreads();

    const int pr = c * 256 + t;
    const int p  = pr >> 5;
    const int r  = pr & 31;

    const float4* wrow = reinterpret_cast<const float4*>(w_out + p * (RANK * RANK) + r * RANK);
    float4 w[8];
    #pragma unroll
    for (int q = 0; q < 8; ++q) w[q] = wrow[q];

    #pragma unroll
    for (int jj = 0; jj < 8; ++jj) {
        float acc = 0.f;
        #pragma unroll
        for (int q = 0; q < 8; ++q) {
            acc += bl[jj * 32 + 4 * q + 0] * w[q].x
                 + bl[jj * 32 + 4 * q + 1] * w[q].y
                 + bl[jj * 32 + 4 * q + 2] * w[q].z
                 + bl[jj * 32 + 4 * q + 3] * w[q].w;
        }
        wb[(size_t)(g * 8 + jj) * 4096 + pr] = __float2bfloat16(acc);
    }
}

// ---------------------------------------------------------------------------
// Kernel 3: r15 body looped over 4 CONSECUTIVE jt per block (fixed ib).
// New mechanism (untested before): TEMPORAL write adjacency -- consecutive
// iterations write adjacent-j 2 KB chunks in the SAME i-rows, so each block
// emits per-row sequential 8 KB streams (vs r15: one 2 KB chunk per row per
// block, neighbors filled by unrelated blocks at uncorrelated times).
// Unchanged vs r15: 256 thr, 32 KB LDS, (256,4) residency, transient af/cin,
// jtg-fast grid (per-XCD wb footprint 512 KB), NT sweep, deferred gamma/beta.
// bfrag is now loop-invariant (same i-rows all 4 iterations).
// C/D map: p = tt*16 + g*4 + r, i = i0 + c (m89-verified, passed r4-r18).
// ---------------------------------------------------------------------------
__global__ __launch_bounds__(256, 4) void k3_mfma(
    const __hip_bfloat16* __restrict__ a_bf, const __hip_bfloat16* __restrict__ wb_bf,
    const float* __restrict__ b_out, const float* __restrict__ lno_g,
    const float* __restrict__ lno_b, float* __restrict__ out)
{
    const int t    = threadIdx.x;
    const int wv   = t >> 6;          // 0..3 -> j within quad
    const int lane = t & 63;
    const int g    = lane >> 4;
    const int c    = lane & 15;
    const int jtg  = blockIdx.x & 31;    // fast dim: jt-group (4 jt each)
    const int ib   = blockIdx.x >> 5;    // 0..31
    const int i0   = ib * 16;

    __shared__ __align__(16) float L[16 * 4 * D_PAIR];   // 32 KB

    const short* a_s = reinterpret_cast<const short*>(a_bf);

    // Loop-invariant: this lane's a-row fragment (i-rows fixed for the block).
    const bf16x8 bfrag = *reinterpret_cast<const bf16x8*>(a_s + (i0 + c) * RANK + g * 8);

    // Phase-2 constants (p fixed per thread across rounds and iterations).
    const int f     = t & 127;        // 128 threads cover one i-row (2 KB)
    const int ihalf = t >> 7;         // 2 rows per round
    const int pb    = (f & 31) * 4;   // this thread's fixed p-slot
    const f32x4 gm4 = *reinterpret_cast<const f32x4*>(lno_g + pb);
    const f32x4 bt4 = *reinterpret_cast<const f32x4*>(lno_b + pb);

    #pragma unroll
    for (int it = 0; it < 4; ++it) {
        const int jt = jtg * 4 + it;     // 4 consecutive jt -> adjacent j-chunks
        const int j0 = jt * 4;
        const int j  = j0 + wv;
        const short* wbj = reinterpret_cast<const short*>(wb_bf) + (size_t)j * 4096;

        if (it) __syncthreads();   // protect LDS reuse between iterations

        // ---- Phase 1: MFMA + LN (transient af/cin loads, r15 pattern) ----
        f32x4 acc[8];
        #pragma unroll
        for (int tt = 0; tt < 8; ++tt) {
            bf16x8 af  = *reinterpret_cast<const bf16x8*>(wbj + (tt * 16 + c) * RANK + g * 8);
            f32x4  cin = *reinterpret_cast<const f32x4*>(b_out + tt * 16 + g * 4);
            acc[tt] = __builtin_amdgcn_mfma_f32_16x16x32_bf16(af, bfrag, cin, 0, 0, 0);
        }

        float s = 0.f, ss = 0.f;
        #pragma unroll
        for (int tt = 0; tt < 8; ++tt) {
            #pragma unroll
            for (int r = 0; r < 4; ++r) { float v = acc[tt][r]; s += v; ss += v * v; }
        }
        s  += __shfl_xor(s, 16);  ss += __shfl_xor(ss, 16);
        s  += __shfl_xor(s, 32);  ss += __shfl_xor(ss, 32);
        const float mean = s * (1.0f / D_PAIR);
        const float var  = ss * (1.0f / D_PAIR) - mean * mean;
        const float rstd = rsqrtf(var + EPS);

        // centered/scaled tile -> LDS, slot-swizzled (bits 4..6 ^= i&7)
        #pragma unroll
        for (int tt = 0; tt < 8; ++tt) {
            f32x4 o;
            #pragma unroll
            for (int r = 0; r < 4; ++r)
                o[r] = (acc[tt][r] - mean) * rstd;
            int off = c * 2048 + wv * 512 + tt * 64 + g * 16;   // bytes
            off ^= (c & 7) << 4;
            *reinterpret_cast<f32x4*>(reinterpret_cast<char*>(L) + off) = o;
        }
        __syncthreads();

        // ---- Phase 2: gamma/beta + coalesced nontemporal sweep store ----
        #pragma unroll
        for (int rnd = 0; rnd < 8; ++rnd) {
            const int i = rnd * 2 + ihalf;
            int off = i * 2048 + f * 16;
            off ^= (i & 7) << 4;
            f32x4 v = *reinterpret_cast<const f32x4*>(reinterpret_cast<const char*>(L) + off);
            f32x4 o;
            #pragma unroll
            for (int r = 0; r < 4; ++r)
                o[r] = v[r] * gm4[r] + bt4[r];
            float* dst = out + (size_t)(i0 + i) * (NROW * D_PAIR) + j0 * D_PAIR + f * 4;
            __builtin_nontemporal_store(o, reinterpret_cast<f32x4*>(dst));
        }
    }
}

// ---------------------------------------------------------------------------
extern "C" void kernel_launch(void* const* d_in, const int* in_sizes, int n_in,
                              void* d_out, int out_size, void* d_ws, size_t ws_size,
                              hipStream_t stream) {
    const float* single_a = (const float*)d_in[0];
    const float* single_b = (const float*)d_in[1];
    const float* ln_g     = (const float*)d_in[2];
    const float* ln_b     = (const float*)d_in[3];
    const float* w_left   = (const float*)d_in[4];
    const float* b_left   = (const float*)d_in[5];
    const float* w_right  = (const float*)d_in[6];
    const float* b_right  = (const float*)d_in[7];
    const float* w_out    = (const float*)d_in[8];
    const float* b_out    = (const float*)d_in[9];
    const float* lno_g    = (const float*)d_in[10];
    const float* lno_b    = (const float*)d_in[11];
    float* out = (float*)d_out;

    float* ws = (float*)d_ws;
    __hip_bfloat16* a_bf   = (__hip_bfloat16*)ws;                    // 512*32 bf16 = 32 KB
    float*          b_proj = ws + 16384;                             // 512*32 f32
    __hip_bfloat16* wb_bf  = (__hip_bfloat16*)(ws + 32768);          // 512*4096 bf16 = 4 MB

    k1_ln_proj<<<2 * NROW, 256, 0, stream>>>(single_a, single_b, ln_g, ln_b,
                                             w_left, b_left, w_right, b_right,
                                             a_bf, b_proj);
    k2_wb<<<1024, 256, 0, stream>>>(b_proj, w_out, wb_bf);
    k3_mfma<<<1024, 256, 0, stream>>>(a_bf, wb_bf, b_out, lno_g, lno_b, out);
}

// Round 20
// 44.614 us; speedup vs baseline: 1.0474x; 1.0474x over previous
//
#include <hip/hip_runtime.h>
#include <hip/hip_bf16.h>
#include <math.h>

#define D_SINGLE 512
#define D_PAIR   128
#define RANK     32
#define NROW     512
#define EPS      1e-5f

typedef __attribute__((ext_vector_type(8))) short bf16x8;  // 8 bf16 = 4 VGPRs
typedef __attribute__((ext_vector_type(4))) float f32x4;

// ---------------------------------------------------------------------------
// Kernel 1 (r8 winner, verbatim): per-row LayerNorm + low-rank projection.
// ---------------------------------------------------------------------------
__global__ __launch_bounds__(256) void k1_ln_proj(
    const float* __restrict__ xa, const float* __restrict__ xb,
    const float* __restrict__ ln_g, const float* __restrict__ ln_b,
    const float* __restrict__ wl, const float* __restrict__ bl,
    const float* __restrict__ wr, const float* __restrict__ br,
    __hip_bfloat16* __restrict__ a_bf, float* __restrict__ b_proj)
{
    const int bid  = blockIdx.x;
    const int row  = bid & (NROW - 1);
    const bool isb = bid >= NROW;
    const float* x    = (isb ? xb : xa) + row * D_SINGLE;
    const float* W    = isb ? wr : wl;
    const float* bias = isb ? br : bl;
    float*           outf = b_proj + row * RANK;
    __hip_bfloat16*  outh = a_bf   + row * RANK;

    __shared__ float xn[D_SINGLE];
    __shared__ float red[8];

    const int t    = threadIdx.x;
    const int wave = t >> 6;
    const int lane = t & 63;

    float x0 = x[t], x1 = x[t + 256];
    float s  = x0 + x1;
    float ss = x0 * x0 + x1 * x1;
    #pragma unroll
    for (int m = 1; m < 64; m <<= 1) {
        s  += __shfl_xor(s, m);
        ss += __shfl_xor(ss, m);
    }
    if (lane == 0) { red[wave] = s; red[4 + wave] = ss; }
    __syncthreads();
    float S    = red[0] + red[1] + red[2] + red[3];
    float SS   = red[4] + red[5] + red[6] + red[7];
    float mean = S * (1.0f / D_SINGLE);
    float var  = SS * (1.0f / D_SINGLE) - mean * mean;
    float rstd = rsqrtf(var + EPS);
    xn[t]       = (x0 - mean) * rstd * ln_g[t]       + ln_b[t];
    xn[t + 256] = (x1 - mean) * rstd * ln_g[t + 256] + ln_b[t + 256];
    __syncthreads();

    #pragma unroll
    for (int q = 0; q < 8; ++q) {
        int r = wave + 4 * q;
        float acc = 0.f;
        #pragma unroll
        for (int tt = 0; tt < 8; ++tt) {
            int k = lane + 64 * tt;
            acc += xn[k] * W[r * D_SINGLE + k];
        }
        #pragma unroll
        for (int m = 1; m < 64; m <<= 1) acc += __shfl_xor(acc, m);
        if (lane == 0) {
            float v = acc + bias[r];
            if (isb) outf[r] = v;
            else     outh[r] = __float2bfloat16(v);
        }
    }
}

// ---------------------------------------------------------------------------
// Kernel 2 (r8 winner, verbatim): wb[j][p*32+r] = sum_s b[j][s]*w_out[p][r*32+s]
// ---------------------------------------------------------------------------
__global__ __launch_bounds__(256) void k2_wb(
    const float* __restrict__ bproj, const float* __restrict__ w_out,
    __hip_bfloat16* __restrict__ wb)
{
    const int g = blockIdx.x >> 4;   // j-group (8 rows of b)
    const int c = blockIdx.x & 15;   // pr chunk
    const int t = threadIdx.x;

    __shared__ float bl[8 * RANK];
    bl[t] = bproj[g * 8 * RANK + t];
    __syncthreads();

    const int pr = c * 256 + t;
    const int p  = pr >> 5;
    const int r  = pr & 31;

    const float4* wrow = reinterpret_cast<const float4*>(w_out + p * (RANK * RANK) + r * RANK);
    float4 w[8];
    #pragma unroll
    for (int q = 0; q < 8; ++q) w[q] = wrow[q];

    #pragma unroll
    for (int jj = 0; jj < 8; ++jj) {
        float acc = 0.f;
        #pragma unroll
        for (int q = 0; q < 8; ++q) {
            acc += bl[jj * 32 + 4 * q + 0] * w[q].x
                 + bl[jj * 32 + 4 * q + 1] * w[q].y
                 + bl[jj * 32 + 4 * q + 2] * w[q].z
                 + bl[jj * 32 + 4 * q + 3] * w[q].w;
        }
        wb[(size_t)(g * 8 + jj) * 4096 + pr] = __float2bfloat16(acc);
    }
}

// ---------------------------------------------------------------------------
// Kernel 3 (r15 winner, byte-identical): MFMA + LN (gamma/beta deferred) +
// swizzled LDS staging + nontemporal sweep stores.
// C/D map: p = tt*16 + g*4 + r, i = i0 + c (m89-verified, passed r4-r19).
// ---------------------------------------------------------------------------
__global__ __launch_bounds__(256, 4) void k3_mfma(
    const __hip_bfloat16* __restrict__ a_bf, const __hip_bfloat16* __restrict__ wb_bf,
    const float* __restrict__ b_out, const float* __restrict__ lno_g,
    const float* __restrict__ lno_b, float* __restrict__ out)
{
    const int t    = threadIdx.x;
    const int wv   = t >> 6;          // 0..3 -> j within quad
    const int lane = t & 63;
    const int g    = lane >> 4;
    const int c    = lane & 15;
    const int jt   = blockIdx.x & 127;   // fast dim -> XCD j-locality
    const int ib   = blockIdx.x >> 7;    // 0..31
    const int j0   = jt * 4;
    const int i0   = ib * 16;
    const int j    = j0 + wv;

    __shared__ __align__(16) float L[16 * 4 * D_PAIR];   // 32 KB

    const short* a_s = reinterpret_cast<const short*>(a_bf);
    const short* wbj = reinterpret_cast<const short*>(wb_bf) + (size_t)j * 4096;

    // ---- Phase 1: MFMA + LN (17 VMEM loads/wave, all transient) ----
    bf16x8 bfrag = *reinterpret_cast<const bf16x8*>(a_s + (i0 + c) * RANK + g * 8);

    f32x4 acc[8];
    #pragma unroll
    for (int tt = 0; tt < 8; ++tt) {
        bf16x8 af  = *reinterpret_cast<const bf16x8*>(wbj + (tt * 16 + c) * RANK + g * 8);
        f32x4  cin = *reinterpret_cast<const f32x4*>(b_out + tt * 16 + g * 4);
        acc[tt] = __builtin_amdgcn_mfma_f32_16x16x32_bf16(af, bfrag, cin, 0, 0, 0);
    }

    float s = 0.f, ss = 0.f;
    #pragma unroll
    for (int tt = 0; tt < 8; ++tt) {
        #pragma unroll
        for (int r = 0; r < 4; ++r) { float v = acc[tt][r]; s += v; ss += v * v; }
    }
    s  += __shfl_xor(s, 16);  ss += __shfl_xor(ss, 16);
    s  += __shfl_xor(s, 32);  ss += __shfl_xor(ss, 32);
    const float mean = s * (1.0f / D_PAIR);
    const float var  = ss * (1.0f / D_PAIR) - mean * mean;
    const float rstd = rsqrtf(var + EPS);

    // centered/scaled tile -> LDS, slot-swizzled (bits 4..6 ^= i&7)
    #pragma unroll
    for (int tt = 0; tt < 8; ++tt) {
        f32x4 o;
        #pragma unroll
        for (int r = 0; r < 4; ++r)
            o[r] = (acc[tt][r] - mean) * rstd;
        int off = c * 2048 + wv * 512 + tt * 64 + g * 16;   // bytes
        off ^= (c & 7) << 4;
        *reinterpret_cast<f32x4*>(reinterpret_cast<char*>(L) + off) = o;
    }
    __syncthreads();

    // ---- Phase 2: gamma/beta + coalesced nontemporal sweep store ----
    const int f     = t & 127;        // 128 threads cover one i-row (2 KB)
    const int ihalf = t >> 7;         // 2 rows per round
    const int pb    = (f & 31) * 4;   // this thread's fixed p-slot
    const f32x4 gm4 = *reinterpret_cast<const f32x4*>(lno_g + pb);
    const f32x4 bt4 = *reinterpret_cast<const f32x4*>(lno_b + pb);
    #pragma unroll
    for (int rnd = 0; rnd < 8; ++rnd) {
        const int i = rnd * 2 + ihalf;
        int off = i * 2048 + f * 16;
        off ^= (i & 7) << 4;
        f32x4 v = *reinterpret_cast<const f32x4*>(reinterpret_cast<const char*>(L) + off);
        f32x4 o;
        #pragma unroll
        for (int r = 0; r < 4; ++r)
            o[r] = v[r] * gm4[r] + bt4[r];
        float* dst = out + (size_t)(i0 + i) * (NROW * D_PAIR) + j0 * D_PAIR + f * 4;
        __builtin_nontemporal_store(o, reinterpret_cast<f32x4*>(dst));
    }
}

// ---------------------------------------------------------------------------
extern "C" void kernel_launch(void* const* d_in, const int* in_sizes, int n_in,
                              void* d_out, int out_size, void* d_ws, size_t ws_size,
                              hipStream_t stream) {
    const float* single_a = (const float*)d_in[0];
    const float* single_b = (const float*)d_in[1];
    const float* ln_g     = (const float*)d_in[2];
    const float* ln_b     = (const float*)d_in[3];
    const float* w_left   = (const float*)d_in[4];
    const float* b_left   = (const float*)d_in[5];
    const float* w_right  = (const float*)d_in[6];
    const float* b_right  = (const float*)d_in[7];
    const float* w_out    = (const float*)d_in[8];
    const float* b_out    = (const float*)d_in[9];
    const float* lno_g    = (const float*)d_in[10];
    const float* lno_b    = (const float*)d_in[11];
    float* out = (float*)d_out;

    float* ws = (float*)d_ws;
    __hip_bfloat16* a_bf   = (__hip_bfloat16*)ws;                    // 512*32 bf16 = 32 KB
    float*          b_proj = ws + 16384;                             // 512*32 f32
    __hip_bfloat16* wb_bf  = (__hip_bfloat16*)(ws + 32768);          // 512*4096 bf16 = 4 MB

    k1_ln_proj<<<2 * NROW, 256, 0, stream>>>(single_a, single_b, ln_g, ln_b,
                                             w_left, b_left, w_right, b_right,
                                             a_bf, b_proj);
    k2_wb<<<1024, 256, 0, stream>>>(b_proj, w_out, wb_bf);
    k3_mfma<<<4096, 256, 0, stream>>>(a_bf, wb_bf, b_out, lno_g, lno_b, out);
}